// Round 2
// baseline (1178.560 us; speedup 1.0000x reference)
//
#include <hip/hip_runtime.h>
#include <hip/hip_bf16.h>
#include <float.h>
#include <math.h>

typedef __bf16 bf16_t;
typedef __bf16 bf16x8 __attribute__((ext_vector_type(8)));
typedef float f32x4 __attribute__((ext_vector_type(4)));
typedef int int4v __attribute__((ext_vector_type(4)));

#define M_TOT 256      // B*R
#define C_CH 512
#define H_F 38
#define W_F 50
#define D_IN 25088     // C*7*7
#define N_H 4096
#define NCLS 21
#define SPLITS 8

// ---------------------------------------------------------------------------
// ROI pool: [B,C,H,W] + rois -> pooled bf16 [256][25088] (c*49 + i*7 + j)
// ---------------------------------------------------------------------------
__global__ void roi_pool_kernel(const float* __restrict__ feat,
                                const int* __restrict__ rois,
                                bf16_t* __restrict__ pooled) {
  int br = blockIdx.x;          // 0..255
  int b = br >> 7;              // / 128
  const int* roi = rois + br * 4;
  int x1 = roi[0], y1 = roi[1], x2 = roi[2], y2 = roi[3];
  int h = y2 - y1 + 1, w = x2 - x1 + 1;
  int rs[7], re[7], cs[7], ce[7];
#pragma unroll
  for (int i = 0; i < 7; ++i) {
    rs[i] = y1 + (i * h) / 7;
    re[i] = y1 + ((i + 1) * h + 6) / 7;
    cs[i] = x1 + (i * w) / 7;
    ce[i] = x1 + ((i + 1) * w + 6) / 7;
  }
  for (int c = threadIdx.x; c < C_CH; c += blockDim.x) {
    const float* plane = feat + ((size_t)b * C_CH + c) * (H_F * W_F);
    bf16_t* outp = pooled + (size_t)br * D_IN + c * 49;
#pragma unroll
    for (int i = 0; i < 7; ++i) {
#pragma unroll
      for (int j = 0; j < 7; ++j) {
        float mv = -FLT_MAX;
        for (int y = rs[i]; y < re[i]; ++y) {
          const float* rowp = plane + y * W_F;
          for (int x = cs[j]; x < ce[j]; ++x) mv = fmaxf(mv, rowp[x]);
        }
        outp[i * 7 + j] = (bf16_t)mv;
      }
    }
  }
}

// ---------------------------------------------------------------------------
// Split-K GEMM: A [256][K] bf16 row-major, Bsrc [K][4096] fp32 row-major.
// Block tile 256x128, 8 waves (4x2) of 64x64, MFMA 16x16x32 bf16.
// Writes partials[s][256][4096].
// ---------------------------------------------------------------------------
__device__ __forceinline__ unsigned int pack_bf2(float lo, float hi) {
  unsigned short a = __builtin_bit_cast(unsigned short, (bf16_t)lo);
  unsigned short b = __builtin_bit_cast(unsigned short, (bf16_t)hi);
  return (unsigned int)a | ((unsigned int)b << 16);
}

__global__ __launch_bounds__(512, 2)
void gemm_splitk(const bf16_t* __restrict__ A, const float* __restrict__ Bsrc,
                 float* __restrict__ part, int K, int Kchunk) {
  __shared__ bf16_t Alds[256][40];   // pad 32->40 (16B) keeps b128 reads aligned
  __shared__ bf16_t Blds[32][130];   // pad 128->130: k-group offset = 16 banks

  int tid = threadIdx.x;
  int ncol0 = blockIdx.x * 128;
  int s = blockIdx.y;
  int k0chunk = s * Kchunk;

  int wid = tid >> 6;
  int lane = tid & 63;
  int l16 = lane & 15;
  int kg = lane >> 4;        // 0..3
  int wr = wid >> 1;         // 0..3 -> +64*wr rows
  int wc = wid & 1;          // 0..1 -> +64*wc cols

  // staging assignment
  int a_row = tid >> 2;              // 0..127 (and +128)
  int a_k0 = (tid & 3) * 8;
  int b_k = tid >> 4;                // 0..31
  int b_n0 = (tid & 15) * 8;

  f32x4 acc[4][4] = {};

  const bf16_t* Abase0 = A + (size_t)a_row * K + k0chunk + a_k0;
  const bf16_t* Abase1 = Abase0 + (size_t)128 * K;
  const float* Bbase = Bsrc + (size_t)(k0chunk + b_k) * N_H + ncol0 + b_n0;

  int4v a0 = *(const int4v*)Abase0;
  int4v a1 = *(const int4v*)Abase1;
  f32x4 br0 = *(const f32x4*)Bbase;
  f32x4 br1 = *(const f32x4*)(Bbase + 4);

  int nsteps = Kchunk >> 5;
  for (int ks = 0; ks < nsteps; ++ks) {
    __syncthreads();
    *(int4v*)&Alds[a_row][a_k0] = a0;
    *(int4v*)&Alds[a_row + 128][a_k0] = a1;
    {
      unsigned int* bdst = (unsigned int*)&Blds[b_k][b_n0];
      bdst[0] = pack_bf2(br0[0], br0[1]);
      bdst[1] = pack_bf2(br0[2], br0[3]);
      bdst[2] = pack_bf2(br1[0], br1[1]);
      bdst[3] = pack_bf2(br1[2], br1[3]);
    }
    if (ks + 1 < nsteps) {
      const bf16_t* pa = Abase0 + (ks + 1) * 32;
      a0 = *(const int4v*)pa;
      a1 = *(const int4v*)(pa + (size_t)128 * K);
      const float* pb = Bbase + (size_t)(ks + 1) * 32 * N_H;
      br0 = *(const f32x4*)pb;
      br1 = *(const f32x4*)(pb + 4);
    }
    __syncthreads();

    bf16x8 af[4];
#pragma unroll
    for (int rr = 0; rr < 4; ++rr)
      af[rr] = *(const bf16x8*)&Alds[wr * 64 + rr * 16 + l16][kg * 8];
#pragma unroll
    for (int cc = 0; cc < 4; ++cc) {
      int col = wc * 64 + cc * 16 + l16;
      bf16x8 bfr;
#pragma unroll
      for (int i = 0; i < 8; ++i) bfr[i] = Blds[kg * 8 + i][col];
#pragma unroll
      for (int rr = 0; rr < 4; ++rr)
        acc[rr][cc] = __builtin_amdgcn_mfma_f32_16x16x32_bf16(af[rr], bfr, acc[rr][cc], 0, 0, 0);
    }
  }

  // epilogue: partials[s][row][col]; C layout col=lane&15, row=(lane>>4)*4+reg
  float* dst = part + (size_t)s * ((size_t)M_TOT * N_H) + ncol0;
#pragma unroll
  for (int rr = 0; rr < 4; ++rr) {
#pragma unroll
    for (int cc = 0; cc < 4; ++cc) {
#pragma unroll
      for (int reg = 0; reg < 4; ++reg) {
        int row = wr * 64 + rr * 16 + kg * 4 + reg;
        int col = wc * 64 + cc * 16 + l16;
        dst[(size_t)row * N_H + col] = acc[rr][cc][reg];
      }
    }
  }
}

// ---------------------------------------------------------------------------
// Reduce split-K partials + bias; write bf16 and/or fp32.
// ---------------------------------------------------------------------------
__global__ void reduce_bias(const float* __restrict__ part, const float* __restrict__ bias,
                            bf16_t* __restrict__ outbf, float* __restrict__ outf) {
  int idx = blockIdx.x * blockDim.x + threadIdx.x;
  if (idx >= M_TOT * N_H) return;
  int n = idx & (N_H - 1);
  float sum = bias[n];
#pragma unroll
  for (int s = 0; s < SPLITS; ++s) sum += part[(size_t)s * ((size_t)M_TOT * N_H) + idx];
  if (outbf) outbf[idx] = (bf16_t)sum;
  if (outf) outf[idx] = sum;
}

// ---------------------------------------------------------------------------
// Per-ROI head: 21 cls dots + 4 gt-class bbox dots, softmax NLL + smooth-L1.
// acc[0]=nll_sum, acc[1]=valid_cnt, acc[2]=sl1_sum
// ---------------------------------------------------------------------------
__global__ void head_loss_kernel(const float* __restrict__ x2, const int* __restrict__ labels,
                                 const float* __restrict__ gtb, const float* __restrict__ Ws,
                                 const float* __restrict__ bs, const float* __restrict__ Wb,
                                 const float* __restrict__ bb, float* __restrict__ acc) {
  int m = blockIdx.x;
  int tid = threadIdx.x;
  int label = labels[m];
  int l = (label == -1) ? 0 : label;

  float p[25];
#pragma unroll
  for (int j = 0; j < 25; ++j) p[j] = 0.f;

  const float* xrow = x2 + (size_t)m * N_H;
  for (int k = tid; k < N_H; k += 256) {
    float xv = xrow[k];
    const float* wsr = Ws + (size_t)k * NCLS;
#pragma unroll
    for (int j = 0; j < NCLS; ++j) p[j] += xv * wsr[j];
    const float* wbr = Wb + (size_t)k * 84 + 4 * l;
#pragma unroll
    for (int d = 0; d < 4; ++d) p[21 + d] += xv * wbr[d];
  }

  __shared__ float red[25][257];
#pragma unroll
  for (int j = 0; j < 25; ++j) red[j][tid] = p[j];
  __syncthreads();
  for (int off = 128; off > 0; off >>= 1) {
    if (tid < off) {
#pragma unroll
      for (int j = 0; j < 25; ++j) red[j][tid] += red[j][tid + off];
    }
    __syncthreads();
  }

  if (tid == 0) {
    float cls[NCLS];
    float mx = -FLT_MAX;
#pragma unroll
    for (int j = 0; j < NCLS; ++j) { cls[j] = red[j][0] + bs[j]; mx = fmaxf(mx, cls[j]); }
    float se = 0.f;
#pragma unroll
    for (int j = 0; j < NCLS; ++j) se += expf(cls[j] - mx);
    float lse = mx + logf(se);
    if (label != -1) {
      atomicAdd(&acc[0], lse - cls[l]);
      atomicAdd(&acc[1], 1.0f);
    }
    if (label > 0) {
      float sl = 0.f;
#pragma unroll
      for (int d = 0; d < 4; ++d) {
        float u = red[21 + d][0] + bb[4 * l + d];
        float dd = fabsf(gtb[m * 4 + d] - u);
        sl += (dd < 1.f) ? 0.5f * dd * dd : dd - 0.5f;
      }
      atomicAdd(&acc[2], sl);
    }
  }
}

__global__ void finalize_kernel(const float* __restrict__ acc, float* __restrict__ out) {
  if (threadIdx.x == 0 && blockIdx.x == 0) {
    float cls = acc[0] / fmaxf(acc[1], 1.0f);
    float bbl = acc[2];
    out[0] = cls;
    out[1] = bbl;
    out[2] = cls + 10.0f * bbl;
  }
}

// ---------------------------------------------------------------------------
extern "C" void kernel_launch(void* const* d_in, const int* in_sizes, int n_in,
                              void* d_out, int out_size, void* d_ws, size_t ws_size,
                              hipStream_t stream) {
  const float* feat = (const float*)d_in[0];
  const int* rois = (const int*)d_in[1];
  const int* labels = (const int*)d_in[2];
  const float* gtb = (const float*)d_in[3];
  const float* W1 = (const float*)d_in[4];
  const float* b1 = (const float*)d_in[5];
  const float* W2 = (const float*)d_in[6];
  const float* b2 = (const float*)d_in[7];
  const float* Wb = (const float*)d_in[8];
  const float* bbv = (const float*)d_in[9];
  const float* Ws = (const float*)d_in[10];
  const float* bsv = (const float*)d_in[11];
  float* out = (float*)d_out;

  char* ws = (char*)d_ws;
  bf16_t* pooled = (bf16_t*)ws;                              // 256*25088*2 = 12,845,056
  bf16_t* x1 = (bf16_t*)(ws + 12845056);                     // 256*4096*2 = 2,097,152
  float* x2 = (float*)(ws + 14942208);                       // 256*4096*4 = 4,194,304
  float* part = (float*)(ws + 19136512);                     // 8*256*4096*4 = 33,554,432
  float* acc = (float*)(ws + 52690944);                      // 16 B

  hipMemsetAsync(acc, 0, 16, stream);

  roi_pool_kernel<<<256, 256, 0, stream>>>(feat, rois, pooled);

  // GEMM1: [256,25088] x [25088,4096]; Kchunk = 25088/8 = 3136
  gemm_splitk<<<dim3(32, SPLITS), 512, 0, stream>>>(pooled, W1, part, D_IN, D_IN / SPLITS);
  reduce_bias<<<(M_TOT * N_H) / 256, 256, 0, stream>>>(part, b1, x1, nullptr);

  // GEMM2: [256,4096] x [4096,4096]; Kchunk = 512
  gemm_splitk<<<dim3(32, SPLITS), 512, 0, stream>>>(x1, W2, part, N_H, N_H / SPLITS);
  reduce_bias<<<(M_TOT * N_H) / 256, 256, 0, stream>>>(part, b2, nullptr, x2);

  head_loss_kernel<<<M_TOT, 256, 0, stream>>>(x2, labels, gtb, Ws, bsv, Wb, bbv, acc);
  finalize_kernel<<<1, 64, 0, stream>>>(acc, out);
}

// Round 3
// 723.858 us; speedup vs baseline: 1.6282x; 1.6282x over previous
//
#include <hip/hip_runtime.h>
#include <hip/hip_bf16.h>
#include <float.h>
#include <math.h>

typedef __bf16 bf16_t;
typedef __bf16 bf16x8 __attribute__((ext_vector_type(8)));
typedef float f32x4 __attribute__((ext_vector_type(4)));
typedef int int4v __attribute__((ext_vector_type(4)));

#define M_TOT 256      // B*R
#define C_CH 512
#define H_F 38
#define W_F 50
#define D_IN 25088     // C*7*7
#define N_H 4096
#define NCLS 21
#define SPLITS 8

// ---------------------------------------------------------------------------
// ROI pool: one thread per output element (br, c, bin). Coalesced bf16 writes,
// scalar fp32 reads served by L2/L3 (feature map is 7.8 MB, fully cached).
// grid = dim3(98, 256), block = 256: idx_in = bx*256+tid in [0,25088)
// ---------------------------------------------------------------------------
__global__ void roi_pool_kernel(const float* __restrict__ feat,
                                const int* __restrict__ rois,
                                bf16_t* __restrict__ pooled) {
  int idx_in = blockIdx.x * 256 + threadIdx.x;   // 0..25087
  int br = blockIdx.y;                           // 0..255
  int b = br >> 7;
  const int* roi = rois + br * 4;
  int x1 = roi[0], y1 = roi[1], x2 = roi[2], y2 = roi[3];
  int h = y2 - y1 + 1, w = x2 - x1 + 1;
  int c = idx_in / 49;
  int bin = idx_in - c * 49;
  int i = bin / 7;
  int j = bin - i * 7;
  int rs = y1 + (i * h) / 7;
  int re = y1 + ((i + 1) * h + 6) / 7;
  int cs = x1 + (j * w) / 7;
  int ce = x1 + ((j + 1) * w + 6) / 7;
  const float* plane = feat + ((size_t)b * C_CH + c) * (H_F * W_F);
  float mv = -FLT_MAX;
  for (int y = rs; y < re; ++y) {
    const float* rp = plane + y * W_F;
    for (int x = cs; x < ce; ++x) mv = fmaxf(mv, rp[x]);
  }
  pooled[(size_t)br * D_IN + idx_in] = (bf16_t)mv;
}

// ---------------------------------------------------------------------------
// Split-K GEMM: A [256][K] bf16 row-major, Bsrc [K][4096] fp32 row-major.
// Block tile 256x128, 8 waves (4x2) of 64x64, MFMA 16x16x32 bf16.
// B staged TRANSPOSED in LDS as [n][k] so both A and B fragment reads are
// contiguous ds_read_b128 (conflict-free with the 80B row stride: bank starts
// = 4*((5n+kg) mod 8) -> 8 lanes per 4-bank group = exactly 8 phases).
// Writes partials[s][256][4096].
// ---------------------------------------------------------------------------
__device__ __forceinline__ unsigned int pack_bf2(float lo, float hi) {
  unsigned short a = __builtin_bit_cast(unsigned short, (bf16_t)lo);
  unsigned short b = __builtin_bit_cast(unsigned short, (bf16_t)hi);
  return (unsigned int)a | ((unsigned int)b << 16);
}

__global__ __launch_bounds__(512, 2)
void gemm_splitk(const bf16_t* __restrict__ A, const float* __restrict__ Bsrc,
                 float* __restrict__ part, int K, int Kchunk) {
  __shared__ bf16_t Alds[256][40];   // [row][k], pad 32->40 (80B stride)
  __shared__ bf16_t Blds[128][40];   // [col][k], transposed, same stride

  int tid = threadIdx.x;
  int ncol0 = blockIdx.x * 128;
  int s = blockIdx.y;
  int k0chunk = s * Kchunk;

  int wid = tid >> 6;
  int lane = tid & 63;
  int l16 = lane & 15;
  int kg = lane >> 4;        // 0..3
  int wr = wid >> 1;         // 0..3 -> +64*wr rows
  int wc = wid & 1;          // 0..1 -> +64*wc cols

  // staging assignment
  int a_row = tid >> 2;              // 0..127 (and +128)
  int a_k0 = (tid & 3) * 8;
  int b_n = tid & 127;               // 0..127 (output col within tile)
  int b_kb = (tid >> 7) * 8;         // 0,8,16,24 (k base)

  f32x4 acc[4][4] = {};

  const bf16_t* Abase0 = A + (size_t)a_row * K + k0chunk + a_k0;
  const bf16_t* Abase1 = Abase0 + (size_t)128 * K;
  const float* Bbase = Bsrc + (size_t)(k0chunk + b_kb) * N_H + ncol0 + b_n;

  int4v a0 = *(const int4v*)Abase0;
  int4v a1 = *(const int4v*)Abase1;
  float br_[8];
#pragma unroll
  for (int jj = 0; jj < 8; ++jj) br_[jj] = Bbase[(size_t)jj * N_H];

  int nsteps = Kchunk >> 5;
  for (int ks = 0; ks < nsteps; ++ks) {
    __syncthreads();
    *(int4v*)&Alds[a_row][a_k0] = a0;
    *(int4v*)&Alds[a_row + 128][a_k0] = a1;
    {
      unsigned int pk[4];
#pragma unroll
      for (int w2 = 0; w2 < 4; ++w2) pk[w2] = pack_bf2(br_[2 * w2], br_[2 * w2 + 1]);
      *(int4v*)&Blds[b_n][b_kb] = *(int4v*)pk;
    }
    if (ks + 1 < nsteps) {
      const bf16_t* pa = Abase0 + (ks + 1) * 32;
      a0 = *(const int4v*)pa;
      a1 = *(const int4v*)(pa + (size_t)128 * K);
      const float* pb = Bbase + (size_t)(ks + 1) * 32 * N_H;
#pragma unroll
      for (int jj = 0; jj < 8; ++jj) br_[jj] = pb[(size_t)jj * N_H];
    }
    __syncthreads();

    bf16x8 af[4];
#pragma unroll
    for (int rr = 0; rr < 4; ++rr)
      af[rr] = *(const bf16x8*)&Alds[wr * 64 + rr * 16 + l16][kg * 8];
#pragma unroll
    for (int cc = 0; cc < 4; ++cc) {
      bf16x8 bfr = *(const bf16x8*)&Blds[wc * 64 + cc * 16 + l16][kg * 8];
#pragma unroll
      for (int rr = 0; rr < 4; ++rr)
        acc[rr][cc] = __builtin_amdgcn_mfma_f32_16x16x32_bf16(af[rr], bfr, acc[rr][cc], 0, 0, 0);
    }
  }

  // epilogue: partials[s][row][col]; C layout col=lane&15, row=(lane>>4)*4+reg
  float* dst = part + (size_t)s * ((size_t)M_TOT * N_H) + ncol0;
#pragma unroll
  for (int rr = 0; rr < 4; ++rr) {
#pragma unroll
    for (int cc = 0; cc < 4; ++cc) {
#pragma unroll
      for (int reg = 0; reg < 4; ++reg) {
        int row = wr * 64 + rr * 16 + kg * 4 + reg;
        int col = wc * 64 + cc * 16 + l16;
        dst[(size_t)row * N_H + col] = acc[rr][cc][reg];
      }
    }
  }
}

// ---------------------------------------------------------------------------
// Reduce split-K partials + bias; write bf16 and/or fp32.
// ---------------------------------------------------------------------------
__global__ void reduce_bias(const float* __restrict__ part, const float* __restrict__ bias,
                            bf16_t* __restrict__ outbf, float* __restrict__ outf) {
  int idx = blockIdx.x * blockDim.x + threadIdx.x;
  if (idx >= M_TOT * N_H) return;
  int n = idx & (N_H - 1);
  float sum = bias[n];
#pragma unroll
  for (int s = 0; s < SPLITS; ++s) sum += part[(size_t)s * ((size_t)M_TOT * N_H) + idx];
  if (outbf) outbf[idx] = (bf16_t)sum;
  if (outf) outf[idx] = sum;
}

// ---------------------------------------------------------------------------
// Per-ROI head: 21 cls dots + 4 gt-class bbox dots, softmax NLL + smooth-L1.
// acc[0]=nll_sum, acc[1]=valid_cnt, acc[2]=sl1_sum
// ---------------------------------------------------------------------------
__global__ void head_loss_kernel(const float* __restrict__ x2, const int* __restrict__ labels,
                                 const float* __restrict__ gtb, const float* __restrict__ Ws,
                                 const float* __restrict__ bs, const float* __restrict__ Wb,
                                 const float* __restrict__ bb, float* __restrict__ acc) {
  int m = blockIdx.x;
  int tid = threadIdx.x;
  int label = labels[m];
  int l = (label == -1) ? 0 : label;

  float p[25];
#pragma unroll
  for (int j = 0; j < 25; ++j) p[j] = 0.f;

  const float* xrow = x2 + (size_t)m * N_H;
  for (int k = tid; k < N_H; k += 256) {
    float xv = xrow[k];
    const float* wsr = Ws + (size_t)k * NCLS;
#pragma unroll
    for (int j = 0; j < NCLS; ++j) p[j] += xv * wsr[j];
    const float* wbr = Wb + (size_t)k * 84 + 4 * l;
#pragma unroll
    for (int d = 0; d < 4; ++d) p[21 + d] += xv * wbr[d];
  }

  __shared__ float red[25][257];
#pragma unroll
  for (int j = 0; j < 25; ++j) red[j][tid] = p[j];
  __syncthreads();
  for (int off = 128; off > 0; off >>= 1) {
    if (tid < off) {
#pragma unroll
      for (int j = 0; j < 25; ++j) red[j][tid] += red[j][tid + off];
    }
    __syncthreads();
  }

  if (tid == 0) {
    float cls[NCLS];
    float mx = -FLT_MAX;
#pragma unroll
    for (int j = 0; j < NCLS; ++j) { cls[j] = red[j][0] + bs[j]; mx = fmaxf(mx, cls[j]); }
    float se = 0.f;
#pragma unroll
    for (int j = 0; j < NCLS; ++j) se += expf(cls[j] - mx);
    float lse = mx + logf(se);
    if (label != -1) {
      atomicAdd(&acc[0], lse - cls[l]);
      atomicAdd(&acc[1], 1.0f);
    }
    if (label > 0) {
      float sl = 0.f;
#pragma unroll
      for (int d = 0; d < 4; ++d) {
        float u = red[21 + d][0] + bb[4 * l + d];
        float dd = fabsf(gtb[m * 4 + d] - u);
        sl += (dd < 1.f) ? 0.5f * dd * dd : dd - 0.5f;
      }
      atomicAdd(&acc[2], sl);
    }
  }
}

__global__ void finalize_kernel(const float* __restrict__ acc, float* __restrict__ out) {
  if (threadIdx.x == 0 && blockIdx.x == 0) {
    float cls = acc[0] / fmaxf(acc[1], 1.0f);
    float bbl = acc[2];
    out[0] = cls;
    out[1] = bbl;
    out[2] = cls + 10.0f * bbl;
  }
}

// ---------------------------------------------------------------------------
extern "C" void kernel_launch(void* const* d_in, const int* in_sizes, int n_in,
                              void* d_out, int out_size, void* d_ws, size_t ws_size,
                              hipStream_t stream) {
  const float* feat = (const float*)d_in[0];
  const int* rois = (const int*)d_in[1];
  const int* labels = (const int*)d_in[2];
  const float* gtb = (const float*)d_in[3];
  const float* W1 = (const float*)d_in[4];
  const float* b1 = (const float*)d_in[5];
  const float* W2 = (const float*)d_in[6];
  const float* b2 = (const float*)d_in[7];
  const float* Wb = (const float*)d_in[8];
  const float* bbv = (const float*)d_in[9];
  const float* Ws = (const float*)d_in[10];
  const float* bsv = (const float*)d_in[11];
  float* out = (float*)d_out;

  char* ws = (char*)d_ws;
  bf16_t* pooled = (bf16_t*)ws;                              // 256*25088*2 = 12,845,056
  bf16_t* x1 = (bf16_t*)(ws + 12845056);                     // 256*4096*2 = 2,097,152
  float* x2 = (float*)(ws + 14942208);                       // 256*4096*4 = 4,194,304
  float* part = (float*)(ws + 19136512);                     // 8*256*4096*4 = 33,554,432
  float* acc = (float*)(ws + 52690944);                      // 16 B

  hipMemsetAsync(acc, 0, 16, stream);

  roi_pool_kernel<<<dim3(98, 256), 256, 0, stream>>>(feat, rois, pooled);

  // GEMM1: [256,25088] x [25088,4096]; Kchunk = 25088/8 = 3136
  gemm_splitk<<<dim3(32, SPLITS), 512, 0, stream>>>(pooled, W1, part, D_IN, D_IN / SPLITS);
  reduce_bias<<<(M_TOT * N_H) / 256, 256, 0, stream>>>(part, b1, x1, nullptr);

  // GEMM2: [256,4096] x [4096,4096]; Kchunk = 512
  gemm_splitk<<<dim3(32, SPLITS), 512, 0, stream>>>(x1, W2, part, N_H, N_H / SPLITS);
  reduce_bias<<<(M_TOT * N_H) / 256, 256, 0, stream>>>(part, b2, nullptr, x2);

  head_loss_kernel<<<M_TOT, 256, 0, stream>>>(x2, labels, gtb, Ws, bsv, Wb, bbv, acc);
  finalize_kernel<<<1, 64, 0, stream>>>(acc, out);
}

// Round 6
// 706.611 us; speedup vs baseline: 1.6679x; 1.0244x over previous
//
#include <hip/hip_runtime.h>
#include <hip/hip_bf16.h>
#include <float.h>
#include <math.h>

typedef __bf16 bf16_t;
typedef __bf16 bf16x8 __attribute__((ext_vector_type(8)));
typedef float f32x4 __attribute__((ext_vector_type(4)));
typedef int int4v __attribute__((ext_vector_type(4)));
typedef int int2v __attribute__((ext_vector_type(2)));

#define M_TOT 256      // B*R
#define C_CH 512
#define H_F 38
#define W_F 50
#define D_IN 25088     // C*7*7
#define N_H 4096
#define NCLS 21
#define SPLITS 8

// ---------------------------------------------------------------------------
// ROI pool: one thread per output element (br, c, bin). Coalesced bf16 writes,
// scalar fp32 reads served by L2/L3 (feature map is 7.8 MB, fully cached).
// ---------------------------------------------------------------------------
__global__ void roi_pool_kernel(const float* __restrict__ feat,
                                const int* __restrict__ rois,
                                bf16_t* __restrict__ pooled) {
  int idx_in = blockIdx.x * 256 + threadIdx.x;   // 0..25087
  int br = blockIdx.y;                           // 0..255
  int b = br >> 7;
  const int* roi = rois + br * 4;
  int x1 = roi[0], y1 = roi[1], x2 = roi[2], y2 = roi[3];
  int h = y2 - y1 + 1, w = x2 - x1 + 1;
  int c = idx_in / 49;
  int bin = idx_in - c * 49;
  int i = bin / 7;
  int j = bin - i * 7;
  int rs = y1 + (i * h) / 7;
  int re = y1 + ((i + 1) * h + 6) / 7;
  int cs = x1 + (j * w) / 7;
  int ce = x1 + ((j + 1) * w + 6) / 7;
  const float* plane = feat + ((size_t)b * C_CH + c) * (H_F * W_F);
  float mv = -FLT_MAX;
  for (int y = rs; y < re; ++y) {
    const float* rp = plane + y * W_F;
    for (int x = cs; x < ce; ++x) mv = fmaxf(mv, rp[x]);
  }
  pooled[(size_t)br * D_IN + idx_in] = (bf16_t)mv;
}

// ---------------------------------------------------------------------------
// Split-K GEMM: A [256][K] bf16 row-major, Bsrc [K][4096] fp32 row-major.
// Block tile 256x128, 8 waves (4x2) of 64x64, MFMA 16x16x32 bf16.
// B staged transposed in LDS [n][k]; both frag reads are conflict-free
// ds_read_b128 (80B row stride -> 8 lanes per 4-bank group per phase).
// 2-deep register prefetch (named buffers) hides the ~900cy HBM latency:
// at compute time, loads for k-steps +1 and +2 are both in flight.
// ---------------------------------------------------------------------------
__device__ __forceinline__ unsigned int pack_bf2(float lo, float hi) {
  unsigned short a = __builtin_bit_cast(unsigned short, (bf16_t)lo);
  unsigned short b = __builtin_bit_cast(unsigned short, (bf16_t)hi);
  return (unsigned int)a | ((unsigned int)b << 16);
}

__global__ __launch_bounds__(512, 2)
void gemm_splitk(const bf16_t* __restrict__ A, const float* __restrict__ Bsrc,
                 float* __restrict__ part, int K, int Kchunk) {
  __shared__ bf16_t Alds[256][40];   // [row][k], pad 32->40 (80B stride)
  __shared__ bf16_t Blds[128][40];   // [col][k], transposed, same stride

  int tid = threadIdx.x;
  int ncol0 = blockIdx.x * 128;
  int s = blockIdx.y;
  int k0chunk = s * Kchunk;

  int wid = tid >> 6;
  int lane = tid & 63;
  int l16 = lane & 15;
  int kg = lane >> 4;        // 0..3
  int wr = wid >> 1;         // 0..3 -> +64*wr rows
  int wc = wid & 1;          // 0..1 -> +64*wc cols

  // staging assignment
  int a_row = tid >> 2;              // 0..127 (and +128)
  int a_k0 = (tid & 3) * 8;
  int b_n = tid & 127;               // 0..127 (output col within tile)
  int b_kb = (tid >> 7) * 8;         // 0,8,16,24 (k base)

  f32x4 acc[4][4] = {};

  const bf16_t* Abase0 = A + (size_t)a_row * K + k0chunk + a_k0;
  const bf16_t* Abase1 = Abase0 + (size_t)128 * K;
  const float* Bbase = Bsrc + (size_t)(k0chunk + b_kb) * N_H + ncol0 + b_n;

  // --- 2-deep prefetch buffers (named; no runtime-indexed reg arrays) ---
  int4v pA0_a, pA1_a; float pB_a[8];
  int4v pA0_b, pA1_b; float pB_b[8];

#define LOADRG(ks, pa0, pa1, pb)                                   \
  {                                                                \
    const bf16_t* pa_ = Abase0 + (ks) * 32;                        \
    pa0 = *(const int4v*)pa_;                                      \
    pa1 = *(const int4v*)(pa_ + (size_t)128 * K);                  \
    const float* pb_ = Bbase + (size_t)(ks) * 32 * N_H;            \
    _Pragma("unroll")                                              \
    for (int jj = 0; jj < 8; ++jj) pb[jj] = pb_[(size_t)jj * N_H]; \
  }

#define STAGE(pa0, pa1, pb)                                        \
  {                                                                \
    *(int4v*)&Alds[a_row][a_k0] = pa0;                             \
    *(int4v*)&Alds[a_row + 128][a_k0] = pa1;                       \
    unsigned int pk_[4];                                           \
    _Pragma("unroll")                                              \
    for (int w2 = 0; w2 < 4; ++w2)                                 \
      pk_[w2] = pack_bf2(pb[2 * w2], pb[2 * w2 + 1]);              \
    *(int4v*)&Blds[b_n][b_kb] = *(int4v*)pk_;                      \
  }

#define COMPUTE()                                                              \
  {                                                                            \
    bf16x8 af[4];                                                              \
    _Pragma("unroll")                                                          \
    for (int rr = 0; rr < 4; ++rr)                                             \
      af[rr] = *(const bf16x8*)&Alds[wr * 64 + rr * 16 + l16][kg * 8];         \
    _Pragma("unroll")                                                          \
    for (int cc = 0; cc < 4; ++cc) {                                           \
      bf16x8 bfr = *(const bf16x8*)&Blds[wc * 64 + cc * 16 + l16][kg * 8];     \
      _Pragma("unroll")                                                        \
      for (int rr = 0; rr < 4; ++rr)                                           \
        acc[rr][cc] =                                                          \
            __builtin_amdgcn_mfma_f32_16x16x32_bf16(af[rr], bfr, acc[rr][cc],  \
                                                    0, 0, 0);                  \
    }                                                                          \
  }

  int nsteps = Kchunk >> 5;          // even for both GEMMs (98, 16)
  LOADRG(0, pA0_a, pA1_a, pB_a);
  LOADRG(1, pA0_b, pA1_b, pB_b);

  for (int ks = 0; ks < nsteps; ks += 2) {
    __syncthreads();
    STAGE(pA0_a, pA1_a, pB_a);
    if (ks + 2 < nsteps) LOADRG(ks + 2, pA0_a, pA1_a, pB_a);
    __syncthreads();
    COMPUTE();

    __syncthreads();
    STAGE(pA0_b, pA1_b, pB_b);
    if (ks + 3 < nsteps) LOADRG(ks + 3, pA0_b, pA1_b, pB_b);
    __syncthreads();
    COMPUTE();
  }
#undef LOADRG
#undef STAGE
#undef COMPUTE

  // epilogue: partials[s][row][col]; C layout col=lane&15, row=(lane>>4)*4+reg
  float* dst = part + (size_t)s * ((size_t)M_TOT * N_H) + ncol0;
#pragma unroll
  for (int rr = 0; rr < 4; ++rr) {
#pragma unroll
    for (int cc = 0; cc < 4; ++cc) {
#pragma unroll
      for (int reg = 0; reg < 4; ++reg) {
        int row = wr * 64 + rr * 16 + kg * 4 + reg;
        int col = wc * 64 + cc * 16 + l16;
        dst[(size_t)row * N_H + col] = acc[rr][cc][reg];
      }
    }
  }
}

// ---------------------------------------------------------------------------
// Reduce split-K partials + bias; vectorized f32x4. Write bf16 and/or fp32.
// grid: (M_TOT*N_H/4)/256 = 1024 blocks.
// ---------------------------------------------------------------------------
__global__ void reduce_bias(const float* __restrict__ part, const float* __restrict__ bias,
                            bf16_t* __restrict__ outbf, float* __restrict__ outf) {
  int idx4 = blockIdx.x * blockDim.x + threadIdx.x;
  int base = idx4 * 4;
  if (base >= M_TOT * N_H) return;
  int n = base & (N_H - 1);
  f32x4 sum = *(const f32x4*)(bias + n);
#pragma unroll
  for (int s = 0; s < SPLITS; ++s)
    sum += *(const f32x4*)(part + (size_t)s * ((size_t)M_TOT * N_H) + base);
  if (outbf) {
    int2v pk;
    pk[0] = (int)pack_bf2(sum[0], sum[1]);
    pk[1] = (int)pack_bf2(sum[2], sum[3]);
    *(int2v*)(outbf + base) = pk;
  }
  if (outf) *(f32x4*)(outf + base) = sum;
}

// ---------------------------------------------------------------------------
// Per-ROI head: 21 cls dots + 4 gt-class bbox dots, softmax NLL + smooth-L1.
// acc[0]=nll_sum, acc[1]=valid_cnt, acc[2]=sl1_sum
// ---------------------------------------------------------------------------
__global__ void head_loss_kernel(const float* __restrict__ x2, const int* __restrict__ labels,
                                 const float* __restrict__ gtb, const float* __restrict__ Ws,
                                 const float* __restrict__ bs, const float* __restrict__ Wb,
                                 const float* __restrict__ bb, float* __restrict__ acc) {
  int m = blockIdx.x;
  int tid = threadIdx.x;
  int label = labels[m];
  int l = (label == -1) ? 0 : label;

  float p[25];
#pragma unroll
  for (int j = 0; j < 25; ++j) p[j] = 0.f;

  const float* xrow = x2 + (size_t)m * N_H;
  for (int k = tid; k < N_H; k += 256) {
    float xv = xrow[k];
    const float* wsr = Ws + (size_t)k * NCLS;
#pragma unroll
    for (int j = 0; j < NCLS; ++j) p[j] += xv * wsr[j];
    const float* wbr = Wb + (size_t)k * 84 + 4 * l;
#pragma unroll
    for (int d = 0; d < 4; ++d) p[21 + d] += xv * wbr[d];
  }

  __shared__ float red[25][257];
#pragma unroll
  for (int j = 0; j < 25; ++j) red[j][tid] = p[j];
  __syncthreads();
  for (int off = 128; off > 0; off >>= 1) {
    if (tid < off) {
#pragma unroll
      for (int j = 0; j < 25; ++j) red[j][tid] += red[j][tid + off];
    }
    __syncthreads();
  }

  if (tid == 0) {
    float cls[NCLS];
    float mx = -FLT_MAX;
#pragma unroll
    for (int j = 0; j < NCLS; ++j) { cls[j] = red[j][0] + bs[j]; mx = fmaxf(mx, cls[j]); }
    float se = 0.f;
#pragma unroll
    for (int j = 0; j < NCLS; ++j) se += expf(cls[j] - mx);
    float lse = mx + logf(se);
    if (label != -1) {
      atomicAdd(&acc[0], lse - cls[l]);
      atomicAdd(&acc[1], 1.0f);
    }
    if (label > 0) {
      float sl = 0.f;
#pragma unroll
      for (int d = 0; d < 4; ++d) {
        float u = red[21 + d][0] + bb[4 * l + d];
        float dd = fabsf(gtb[m * 4 + d] - u);
        sl += (dd < 1.f) ? 0.5f * dd * dd : dd - 0.5f;
      }
      atomicAdd(&acc[2], sl);
    }
  }
}

__global__ void finalize_kernel(const float* __restrict__ acc, float* __restrict__ out) {
  if (threadIdx.x == 0 && blockIdx.x == 0) {
    float cls = acc[0] / fmaxf(acc[1], 1.0f);
    float bbl = acc[2];
    out[0] = cls;
    out[1] = bbl;
    out[2] = cls + 10.0f * bbl;
  }
}

// ---------------------------------------------------------------------------
extern "C" void kernel_launch(void* const* d_in, const int* in_sizes, int n_in,
                              void* d_out, int out_size, void* d_ws, size_t ws_size,
                              hipStream_t stream) {
  const float* feat = (const float*)d_in[0];
  const int* rois = (const int*)d_in[1];
  const int* labels = (const int*)d_in[2];
  const float* gtb = (const float*)d_in[3];
  const float* W1 = (const float*)d_in[4];
  const float* b1 = (const float*)d_in[5];
  const float* W2 = (const float*)d_in[6];
  const float* b2 = (const float*)d_in[7];
  const float* Wb = (const float*)d_in[8];
  const float* bbv = (const float*)d_in[9];
  const float* Ws = (const float*)d_in[10];
  const float* bsv = (const float*)d_in[11];
  float* out = (float*)d_out;

  char* ws = (char*)d_ws;
  bf16_t* pooled = (bf16_t*)ws;                              // 256*25088*2 = 12,845,056
  bf16_t* x1 = (bf16_t*)(ws + 12845056);                     // 256*4096*2 = 2,097,152
  float* x2 = (float*)(ws + 14942208);                       // 256*4096*4 = 4,194,304
  float* part = (float*)(ws + 19136512);                     // 8*256*4096*4 = 33,554,432
  float* acc = (float*)(ws + 52690944);                      // 16 B

  hipMemsetAsync(acc, 0, 16, stream);

  roi_pool_kernel<<<dim3(98, 256), 256, 0, stream>>>(feat, rois, pooled);

  // GEMM1: [256,25088] x [25088,4096]; Kchunk = 25088/8 = 3136 -> 98 steps
  gemm_splitk<<<dim3(32, SPLITS), 512, 0, stream>>>(pooled, W1, part, D_IN, D_IN / SPLITS);
  reduce_bias<<<(M_TOT * N_H) / 1024, 256, 0, stream>>>(part, b1, x1, nullptr);

  // GEMM2: [256,4096] x [4096,4096]; Kchunk = 512 -> 16 steps
  gemm_splitk<<<dim3(32, SPLITS), 512, 0, stream>>>(x1, W2, part, N_H, N_H / SPLITS);
  reduce_bias<<<(M_TOT * N_H) / 1024, 256, 0, stream>>>(part, b2, nullptr, x2);

  head_loss_kernel<<<M_TOT, 256, 0, stream>>>(x2, labels, gtb, Ws, bsv, Wb, bbv, acc);
  finalize_kernel<<<1, 64, 0, stream>>>(acc, out);
}